// Round 2
// baseline (7122.411 us; speedup 1.0000x reference)
//
#include <hip/hip_runtime.h>
#include <hip/hip_bf16.h>

// UniPhyBlock: B=2,T=16,D=64,H=64,W=64. Outputs bf16; internal f32.
// Input dtype (bf16 vs f32) auto-detected at runtime (flag in ws).
// Pipeline: detect -> convert -> kA(LN) -> kB(conv3x3) -> kC(x@E + mean)
//   -> kD(flux scan) -> kE(time scan, h_out) -> kF1(x@Dec + LN) -> kMLP(z out)
// Workspace: 3 big buffers with liveness reuse, ~193 MiB total:
//   BUFA: xc -> x_eig -> u_out(in-place) -> dn(in-place)
//   BUFB: xn -> decoded
//   BUFC: xupd (live to the end)

typedef __hip_bfloat16 bf16;
#define DEV __device__ __forceinline__

DEV float b2f(const bf16 x) { return __bfloat162float(x); }
DEV bf16  f2b(float x)      { return __float2bfloat16(x); }
DEV float softplusf(float x){ return x > 20.f ? x : log1pf(expf(x)); }

static constexpr int B_ = 2, T_ = 16, D_ = 64, HW = 4096;
static constexpr int NPIX = B_ * T_ * HW;               // 131072
static constexpr long long N1 = (long long)NPIX * 128;  // 16777216

// workspace offsets (floats). Total = 50,645,056 floats = 193.2 MiB.
static constexpr long long BUFA  = 0;
static constexpr long long BUFB  = N1;
static constexpr long long BUFC  = 2 * N1;
static constexpr long long XMEAN = 3 * N1;             // 4096
static constexpr long long TABS  = XMEAN + 4096;       // 7 * 2048
static constexpr long long FLAGO = TABS + 14336;       // 64 reserved
static constexpr long long WCF   = FLAGO + 64;         // 147456
static constexpr long long W1F   = WCF + 147456;       // 65536
static constexpr long long W2F   = W1F + 65536;        // 65536
static constexpr long long EF    = W2F + 65536;        // Er,Ei,Dr,Di (4096 each)

// out offsets (elements, dtype-independent)
static constexpr long long ZOUT = 0;
static constexpr long long HOUT = 16777216;
static constexpr long long FOUT = 17825792;

// runtime-dtype input load
DEV float ld(const void* p, long long i, bool bf) {
    if (bf) return b2f(((const bf16*)p)[i]);
    return ((const float*)p)[i];
}

// ---- dtype detection: bf16 halfwords all have sane exponent fields ----------
__global__ void k_detect(const unsigned short* __restrict__ x, float* __restrict__ ws) {
    int lane = threadIdx.x;           // 64 threads
    int cnt = 0;
    for (int i = lane; i < 256; i += 64) {
        int e = (x[i] >> 7) & 0xFF;
        cnt += (e >= 100 && e <= 140) ? 1 : 0;
    }
    for (int m = 1; m < 64; m <<= 1) cnt += __shfl_xor(cnt, m, 64);
    if (lane == 0) ws[FLAGO] = (cnt >= 224) ? 1.f : 0.f;
}

// ---- weight -> f32 pre-convert ----------------------------------------------
__global__ void k_convert(const void* Wc, const void* W1, const void* W2,
                          const void* Er, const void* Ei, const void* Dr, const void* Di,
                          float* ws) {
    bool bf = ws[FLAGO] != 0.f;
    int i = blockIdx.x * 256 + threadIdx.x;
    if (i < 147456) { ws[WCF + i] = ld(Wc, i, bf); return; } i -= 147456;
    if (i < 65536)  { ws[W1F + i] = ld(W1, i, bf); return; } i -= 65536;
    if (i < 65536)  { ws[W2F + i] = ld(W2, i, bf); return; } i -= 65536;
    if (i < 4096)   { ws[EF + i]         = ld(Er, i, bf); return; } i -= 4096;
    if (i < 4096)   { ws[EF + 4096 + i]  = ld(Ei, i, bf); return; } i -= 4096;
    if (i < 4096)   { ws[EF + 8192 + i]  = ld(Dr, i, bf); return; } i -= 4096;
    if (i < 4096)   { ws[EF + 12288 + i] = ld(Di, i, bf); return; }
}

// ---- stage A: moveaxis + LN -------------------------------------------------
__global__ __launch_bounds__(256) void kA_ln(const void* __restrict__ xre,
                                             const void* __restrict__ xim,
                                             const void* __restrict__ gs,
                                             const void* __restrict__ bs,
                                             float* __restrict__ ws) {
    bool bf = ws[FLAGO] != 0.f;
    int p = blockIdx.x * 256 + threadIdx.x;   // pixel-timestep 0..131071
    int bt = p >> 12, pix = p & 4095;
    long long ibase = (long long)bt * 64 * HW + pix;
    float s = 0.f, ss = 0.f;
    for (int d = 0; d < 64; d++) {
        float r = ld(xre, ibase + (long long)d * HW, bf);
        float q = ld(xim, ibase + (long long)d * HW, bf);
        s += r + q; ss += r * r + q * q;
    }
    float m = s * (1.f / 128.f);
    float rstd = rsqrtf(ss * (1.f / 128.f) - m * m + 1e-5f);
    float* xc = ws + BUFA + (long long)p * 128;
    float* xn = ws + BUFB + (long long)p * 128;
    for (int d = 0; d < 64; d++) {
        float r = ld(xre, ibase + (long long)d * HW, bf);
        float q = ld(xim, ibase + (long long)d * HW, bf);
        xc[d] = r; xc[d + 64] = q;
        xn[d]      = (r - m) * rstd * ld(gs, d, bf)      + ld(bs, d, bf);
        xn[d + 64] = (q - m) * rstd * ld(gs, d + 64, bf) + ld(bs, d + 64, bf);
    }
}

// ---- stage B: 3x3 conv 128->128, SAME, + x + bc -> xupd ---------------------
__global__ __launch_bounds__(256) void kB_conv(const void* __restrict__ bc,
                                               float* __restrict__ ws) {
    __shared__ float xt[3][32][68];   // [row][ic][col]; col0 <-> w=-1
    bool bf = ws[FLAGO] != 0.f;
    int blk = blockIdx.x;
    int bt = blk >> 6, h = blk & 63;
    int tid = threadIdx.x;
    int oc4 = (tid & 31) * 4;
    int wbase = (tid >> 5) * 8;
    float acc[8][4] = {};
    const float* xn = ws + BUFB;
    const float* wc = ws + WCF;
    for (int icb = 0; icb < 128; icb += 32) {
        __syncthreads();
        for (int l = tid; l < 3 * 66 * 32; l += 256) {
            int r = l / 2112, rem = l - r * 2112;
            int wcl = rem >> 5, ic = rem & 31;
            int hr = h - 1 + r, wr = wcl - 1;
            float v = 0.f;
            if (hr >= 0 && hr < 64 && wr >= 0 && wr < 64)
                v = xn[(long long)(bt * 4096 + hr * 64 + wr) * 128 + icb + ic];
            xt[r][ic][wcl] = v;
        }
        __syncthreads();
        for (int tap = 0; tap < 9; tap++) {
            int dy = tap / 3, dx = tap - dy * 3;
            const float* wrow = wc + ((long long)tap * 128 + icb) * 128 + oc4;
            for (int ic = 0; ic < 32; ic++) {
                float4 wv = *(const float4*)(wrow + ic * 128);
                const float* xrow = &xt[dy][ic][wbase + dx];
                #pragma unroll
                for (int j = 0; j < 8; j++) {
                    float xv = xrow[j];
                    acc[j][0] += xv * wv.x; acc[j][1] += xv * wv.y;
                    acc[j][2] += xv * wv.z; acc[j][3] += xv * wv.w;
                }
            }
        }
    }
    float bcv0 = ld(bc, oc4, bf),     bcv1 = ld(bc, oc4 + 1, bf);
    float bcv2 = ld(bc, oc4 + 2, bf), bcv3 = ld(bc, oc4 + 3, bf);
    long long pbase = (long long)(bt * 4096 + h * 64 + wbase) * 128;
    #pragma unroll
    for (int j = 0; j < 8; j++) {
        float4 xv = *(const float4*)(ws + BUFA + pbase + j * 128 + oc4);
        float4 o;
        o.x = acc[j][0] + xv.x + bcv0; o.y = acc[j][1] + xv.y + bcv1;
        o.z = acc[j][2] + xv.z + bcv2; o.w = acc[j][3] + xv.w + bcv3;
        *(float4*)(ws + BUFC + pbase + j * 128 + oc4) = o;
    }
}

// ---- stage C: x_eig = xupd @ (Er + i Ei), + x_mean accumulation -------------
__global__ __launch_bounds__(256) void kC_eig(float* __restrict__ ws) {
    __shared__ float tile[64][129];
    int blk = blockIdx.x;
    long long px0 = (long long)blk * 64;
    int bt = blk >> 6;
    int tid = threadIdx.x;
    const float* xu = ws + BUFC + px0 * 128;
    for (int l = tid; l < 8192; l += 256) tile[l >> 7][l & 127] = xu[l];
    __syncthreads();
    int px = tid & 63, eg = tid >> 6, e0 = eg * 16;
    const float* Er = ws + EF;
    const float* Ei = ws + EF + 4096;
    float ar[16] = {}, ai[16] = {};
    for (int d = 0; d < 64; d++) {
        float xr = tile[px][d], xi = tile[px][64 + d];
        const float* er = Er + d * 64 + e0;
        const float* ei = Ei + d * 64 + e0;
        #pragma unroll
        for (int j = 0; j < 16; j += 4) {
            float4 wr = *(const float4*)(er + j);
            float4 wi = *(const float4*)(ei + j);
            ar[j]     += xr * wr.x - xi * wi.x;  ai[j]     += xr * wi.x + xi * wr.x;
            ar[j + 1] += xr * wr.y - xi * wi.y;  ai[j + 1] += xr * wi.y + xi * wr.y;
            ar[j + 2] += xr * wr.z - xi * wi.z;  ai[j + 2] += xr * wi.z + xi * wr.z;
            ar[j + 3] += xr * wr.w - xi * wi.w;  ai[j + 3] += xr * wi.w + xi * wr.w;
        }
    }
    // wave reduce (lanes = 64 pixels) -> x_mean sums
    #pragma unroll
    for (int k = 0; k < 16; k++) {
        float sr = ar[k], si = ai[k];
        for (int msk = 1; msk < 64; msk <<= 1) {
            sr += __shfl_xor(sr, msk, 64);
            si += __shfl_xor(si, msk, 64);
        }
        if (px == 0) {
            atomicAdd(ws + XMEAN + bt * 128 + e0 + k, sr);
            atomicAdd(ws + XMEAN + bt * 128 + e0 + k + 64, si);
        }
    }
    __syncthreads();
    #pragma unroll
    for (int k = 0; k < 16; k++) { tile[px][e0 + k] = ar[k]; tile[px][64 + e0 + k] = ai[k]; }
    __syncthreads();
    float* xe = ws + BUFA + px0 * 128;   // overwrite xc (dead after kB)
    for (int l = tid; l < 8192; l += 256) xe[l] = tile[l >> 7][l & 127];
}

// ---- stage D: flux recurrence, source, gate, op tables, flux_out ------------
__global__ __launch_bounds__(256) void kD_flux(const void* __restrict__ fxr, const void* __restrict__ fxi,
                                               const void* __restrict__ dtseq, const void* __restrict__ lamflux,
                                               const void* __restrict__ Wsr, const void* __restrict__ Wsi,
                                               const void* __restrict__ wgate, const void* __restrict__ bgate,
                                               const void* __restrict__ lamreraw, const void* __restrict__ lamim,
                                               float* __restrict__ ws, void* __restrict__ outv) {
    bool bfo = ws[FLAGO] != 0.f;
    int b = blockIdx.x;
    int tid = threadIdx.x;
    int d = tid & 63, g = tid >> 6;
    __shared__ float fr[64], fi[64], psr[4][64], psi[4][64];
    float lam_f = softplusf(ld(lamflux, d, bfo));
    float lre = -softplusf(ld(lamreraw, d, bfo));
    float lim = ld(lamim, d, bfo);
    float cr = 0.f, ci = 0.f;
    if (g == 0) { cr = ld(fxr, b * 64 + d, bfo); ci = ld(fxi, b * 64 + d, bfo); }
    float* tabs = ws + TABS;
    const float* xmean = ws + XMEAN;
    for (int t = 0; t < 16; t++) {
        float dt = ld(dtseq, b * 16 + t, bfo);
        int idx = b * 1024 + t * 64 + d;
        if (g == 0) {
            float A = expf(-lam_f * dt);
            float xr = xmean[(b * 16 + t) * 128 + d]      * (1.f / 4096.f) * dt;
            float xq = xmean[(b * 16 + t) * 128 + 64 + d] * (1.f / 4096.f) * dt;
            cr = A * cr + xr; ci = A * ci + xq;
            fr[d] = cr; fi[d] = ci;
        }
        __syncthreads();
        {   // source partials: out channel e = d, rows g*16..g*16+15
            float pr = 0.f, pi = 0.f;
            #pragma unroll
            for (int k = 0; k < 16; k++) {
                int d2 = g * 16 + k;
                float wr = ld(Wsr, d2 * 64 + d, bfo), wi = ld(Wsi, d2 * 64 + d, bfo);
                pr += fr[d2] * wr - fi[d2] * wi;
                pi += fr[d2] * wi + fi[d2] * wr;
            }
            psr[g][d] = pr; psi[g][d] = pi;
        }
        if (g == 1) {
            float od  = expf(lre * dt);
            float odr = od * cosf(lim * dt);
            float odi = od * sinf(lim * dt);
            tabs[3 * 2048 + idx] = odr; tabs[4 * 2048 + idx] = odi;
            float den = lre * lre + lim * lim;
            float tr = odr - 1.f;
            tabs[5 * 2048 + idx] = (tr * lre + odi * lim) / den;
            tabs[6 * 2048 + idx] = (odi * lre - tr * lim) / den;
        }
        __syncthreads();
        if (g == 0) {
            float sr = psr[0][d] + psr[1][d] + psr[2][d] + psr[3][d];
            float si = psi[0][d] + psi[1][d] + psi[2][d] + psi[3][d];
            tabs[1 * 2048 + idx] = sr; tabs[2 * 2048 + idx] = si;
            tabs[0 * 2048 + idx] = 1.f / (1.f + expf(-(cr * ld(wgate, d, bfo) + ld(bgate, d, bfo))));
            if (t == 15) {
                if (bfo) {
                    bf16* ob = (bf16*)outv;
                    ob[FOUT + (b * 64 + d) * 2]     = f2b(cr);
                    ob[FOUT + (b * 64 + d) * 2 + 1] = f2b(ci);
                } else {
                    float* of = (float*)outv;
                    of[FOUT + (b * 64 + d) * 2]     = cr;
                    of[FOUT + (b * 64 + d) * 2 + 1] = ci;
                }
            }
        }
    }
}

// ---- stage E: per-(b,h,w,d) time recurrence, u_out (in-place) + h_out -------
__global__ __launch_bounds__(256) void kE_scan(const void* __restrict__ hre,
                                               const void* __restrict__ him,
                                               float* __restrict__ ws, void* __restrict__ outv) {
    __shared__ float tab[7][16][64];
    bool bfo = ws[FLAGO] != 0.f;
    long long G = (long long)blockIdx.x * 256 + threadIdx.x;
    int d = threadIdx.x & 63;
    int pix = (int)((G >> 6) & 4095);
    int b = (int)(G >> 18);
    const float* tabs = ws + TABS;
    for (int l = threadIdx.x; l < 7 * 1024; l += 256) {
        int a = l >> 10, idx = l & 1023;
        ((float*)tab)[l] = tabs[a * 2048 + b * 1024 + idx];
    }
    __syncthreads();
    long long hidx = ((long long)b * 4096 + pix) * 64 + d;
    float cr = ld(hre, hidx, bfo), ci = ld(him, hidx, bfo);
    float* xe = ws + BUFA;            // read x_eig, write u_out in place
    for (int t = 0; t < 16; t++) {
        long long base = ((long long)((b * 16 + t) * 4096 + pix)) * 128 + d;
        float xr = xe[base], xi = xe[base + 64];
        float gt = tab[0][t][d], sr = tab[1][t][d], si = tab[2][t][d];
        float odr = tab[3][t][d], odi = tab[4][t][d];
        float ofr = tab[5][t][d], ofi = tab[6][t][d];
        float fre = xr * gt + sr * (1.f - gt);
        float fim = xi * gt + si * (1.f - gt);
        float ure = fre * ofr - fim * ofi;
        float uim = fre * ofi + fim * ofr;
        float ncr = odr * cr - odi * ci + ure;
        float nci = odr * ci + odi * cr + uim;
        cr = ncr; ci = nci;
        xe[base] = cr; xe[base + 64] = ci;
    }
    if (bfo) {
        __hip_bfloat162 hv; hv.x = f2b(cr); hv.y = f2b(ci);
        ((__hip_bfloat162*)((bf16*)outv + HOUT))[hidx] = hv;
    } else {
        float2 hv; hv.x = cr; hv.y = ci;
        ((float2*)((float*)outv + HOUT))[hidx] = hv;
    }
}

// ---- stage F1: decoded = u_out @ Dec (-> BUFB), + LN -> dn (in-place BUFA) --
__global__ __launch_bounds__(256) void kF1_dec(const void* __restrict__ gt_,
                                               const void* __restrict__ bt_,
                                               float* __restrict__ ws) {
    __shared__ float tile[64][129];
    __shared__ float mS[64], rS[64];
    bool bf = ws[FLAGO] != 0.f;
    long long px0 = (long long)blockIdx.x * 64;
    int tid = threadIdx.x;
    const float* uo = ws + BUFA + px0 * 128;
    for (int l = tid; l < 8192; l += 256) tile[l >> 7][l & 127] = uo[l];
    __syncthreads();
    int px = tid & 63, eg = tid >> 6, e0 = eg * 16;
    const float* Dr = ws + EF + 8192;
    const float* Di = ws + EF + 12288;
    float ar[16] = {}, ai[16] = {};
    for (int d = 0; d < 64; d++) {
        float xr = tile[px][d], xi = tile[px][64 + d];
        const float* er = Dr + d * 64 + e0;
        const float* ei = Di + d * 64 + e0;
        #pragma unroll
        for (int j = 0; j < 16; j += 4) {
            float4 wr = *(const float4*)(er + j);
            float4 wi = *(const float4*)(ei + j);
            ar[j]     += xr * wr.x - xi * wi.x;  ai[j]     += xr * wi.x + xi * wr.x;
            ar[j + 1] += xr * wr.y - xi * wi.y;  ai[j + 1] += xr * wi.y + xi * wr.y;
            ar[j + 2] += xr * wr.z - xi * wi.z;  ai[j + 2] += xr * wi.z + xi * wr.z;
            ar[j + 3] += xr * wr.w - xi * wi.w;  ai[j + 3] += xr * wi.w + xi * wr.w;
        }
    }
    __syncthreads();
    #pragma unroll
    for (int k = 0; k < 16; k++) { tile[px][e0 + k] = ar[k]; tile[px][64 + e0 + k] = ai[k]; }
    __syncthreads();
    float* dec = ws + BUFB + px0 * 128;    // overwrite xn (dead)
    for (int l = tid; l < 8192; l += 256) dec[l] = tile[l >> 7][l & 127];
    if (tid < 64) {
        float s = 0.f, ss = 0.f;
        for (int ch = 0; ch < 128; ch++) { float v = tile[tid][ch]; s += v; ss += v * v; }
        float m = s * (1.f / 128.f);
        mS[tid] = m;
        rS[tid] = rsqrtf(ss * (1.f / 128.f) - m * m + 1e-5f);
    }
    __syncthreads();
    float* dn = ws + BUFA + px0 * 128;     // overwrite u_out (dead after this)
    for (int l = tid; l < 8192; l += 256) {
        int p2 = l >> 7, ch = l & 127;
        dn[l] = (tile[p2][ch] - mS[p2]) * rS[p2] * ld(gt_, ch, bf) + ld(bt_, ch, bf);
    }
}

// ---- stage F2+F3 fused: MLP + z write ---------------------------------------
__global__ __launch_bounds__(256) void kMLP(const void* __restrict__ b1v,
                                            const void* __restrict__ b2v,
                                            float* __restrict__ ws, void* __restrict__ outv) {
    __shared__ float dnl[32][130];
    __shared__ float h1l[32][68];
    bool bf = ws[FLAGO] != 0.f;
    long long px0 = (long long)blockIdx.x * 32;
    int tid = threadIdx.x;
    const float* dn = ws + BUFA + px0 * 128;
    for (int l = tid; l < 4096; l += 256) dnl[l >> 7][l & 127] = dn[l];
    int pxl = tid >> 3;   // 0..31
    int og = tid & 7;     // 0..7
    float d2a[16];
    #pragma unroll
    for (int j = 0; j < 4; j++)
        #pragma unroll
        for (int c = 0; c < 4; c++)
            d2a[j * 4 + c] = ld(b2v, og * 4 + c + j * 32, bf);
    const float* W1p = ws + W1F;
    const float* W2p = ws + W2F;
    __syncthreads();
    for (int fc = 0; fc < 8; fc++) {
        float h[8];
        int fbase = fc * 64 + og * 8;
        #pragma unroll
        for (int k = 0; k < 8; k++) h[k] = ld(b1v, fbase + k, bf);
        for (int ic = 0; ic < 128; ic++) {
            float a = dnl[pxl][ic];
            float4 w0 = *(const float4*)(W1p + ic * 512 + fbase);
            float4 w1 = *(const float4*)(W1p + ic * 512 + fbase + 4);
            h[0] += a * w0.x; h[1] += a * w0.y; h[2] += a * w0.z; h[3] += a * w0.w;
            h[4] += a * w1.x; h[5] += a * w1.y; h[6] += a * w1.z; h[7] += a * w1.w;
        }
        __syncthreads();   // previous fc's h1l reads complete
        #pragma unroll
        for (int k = 0; k < 8; k++) {
            float x = h[k];
            float th = tanhf(0.7978845608028654f * (x + 0.044715f * x * x * x));
            h1l[pxl][og * 8 + k] = 0.5f * x * (1.f + th);
        }
        __syncthreads();
        for (int ic = 0; ic < 64; ic++) {
            float a = h1l[pxl][ic];
            #pragma unroll
            for (int j = 0; j < 4; j++) {
                float4 w = *(const float4*)(W2p + (fc * 64 + ic) * 128 + og * 4 + j * 32);
                d2a[j * 4 + 0] += a * w.x; d2a[j * 4 + 1] += a * w.y;
                d2a[j * 4 + 2] += a * w.z; d2a[j * 4 + 3] += a * w.w;
            }
        }
    }
    long long pxg = px0 + pxl;
    const float* xu  = ws + BUFC + pxg * 128;
    const float* dec = ws + BUFB + pxg * 128;
    #pragma unroll
    for (int j2 = 0; j2 < 2; j2++)
        #pragma unroll
        for (int c = 0; c < 4; c++) {
            int d = og * 4 + c + j2 * 32;
            float dre = d2a[j2 * 4 + c];
            float dim = d2a[(j2 + 2) * 4 + c];
            float zr = xu[d]      + dec[d]      + dre;
            float zi = xu[d + 64] + dec[d + 64] + dim;
            if (bf) {
                __hip_bfloat162 v; v.x = f2b(zr); v.y = f2b(zi);
                ((__hip_bfloat162*)((bf16*)outv + ZOUT))[pxg * 64 + d] = v;
            } else {
                float2 v; v.x = zr; v.y = zi;
                ((float2*)((float*)outv + ZOUT))[pxg * 64 + d] = v;
            }
        }
}

extern "C" void kernel_launch(void* const* d_in, const int* in_sizes, int n_in,
                              void* d_out, int out_size, void* d_ws, size_t ws_size,
                              hipStream_t stream) {
    const void* x_re  = d_in[0];
    const void* x_im  = d_in[1];
    const void* h_re  = d_in[2];
    const void* h_im  = d_in[3];
    const void* fl_re = d_in[4];
    const void* fl_im = d_in[5];
    const void* dtseq = d_in[6];
    const void* g_s   = d_in[7];
    const void* b_s   = d_in[8];
    const void* Wc    = d_in[9];
    const void* bc    = d_in[10];
    const void* g_t   = d_in[11];
    const void* b_t   = d_in[12];
    const void* E_re  = d_in[13];
    const void* E_im  = d_in[14];
    const void* De_re = d_in[15];
    const void* De_im = d_in[16];
    const void* lamfl = d_in[17];
    const void* Ws_re = d_in[18];
    const void* Ws_im = d_in[19];
    const void* wgate = d_in[20];
    const void* bgate = d_in[21];
    const void* lamrr = d_in[22];
    const void* lamim = d_in[23];
    const void* W1    = d_in[24];
    const void* b1    = d_in[25];
    const void* W2    = d_in[26];
    const void* b2    = d_in[27];
    float* ws = (float*)d_ws;

    hipMemsetAsync((char*)d_ws + XMEAN * sizeof(float), 0, 4096 * sizeof(float), stream);
    k_detect<<<1, 64, 0, stream>>>((const unsigned short*)x_re, ws);
    k_convert<<<1152, 256, 0, stream>>>(Wc, W1, W2, E_re, E_im, De_re, De_im, ws);
    kA_ln<<<512, 256, 0, stream>>>(x_re, x_im, g_s, b_s, ws);
    kB_conv<<<2048, 256, 0, stream>>>(bc, ws);
    kC_eig<<<2048, 256, 0, stream>>>(ws);
    kD_flux<<<2, 256, 0, stream>>>(fl_re, fl_im, dtseq, lamfl, Ws_re, Ws_im,
                                   wgate, bgate, lamrr, lamim, ws, d_out);
    kE_scan<<<2048, 256, 0, stream>>>(h_re, h_im, ws, d_out);
    kF1_dec<<<2048, 256, 0, stream>>>(g_t, b_t, ws);
    kMLP<<<4096, 256, 0, stream>>>(b1, b2, ws, d_out);
}

// Round 5
// 512.256 us; speedup vs baseline: 13.9040x; 13.9040x over previous
//
#include <hip/hip_runtime.h>
#include <hip/hip_bf16.h>

// UniPhyBlock: B=2,T=16,D=64,H=64,W=64. Outputs bf16; internal f32 accum,
// bf16 MFMA for conv / eig / dec / MLP. Input dtype auto-detected.
// Pipeline: detect -> convert(pack) -> kA(LN, bf16 out) -> kB(conv3x3 MFMA)
//   -> kC(eig MFMA + mean) -> kD(flux scan) -> kE(time scan, h_out)
//   -> kF1(dec MFMA + LN) -> kMLP(MFMA MLP + z out)
// Workspace 192.7 MiB (<= round-2-proven 193.2).

typedef __hip_bfloat16 bf16;
typedef __attribute__((ext_vector_type(8))) short bhalf8;   // 8 bf16 (4 VGPR)
typedef __attribute__((ext_vector_type(4))) float floatx4;  // MFMA C/D

#define DEV __device__ __forceinline__

DEV float b2f(const bf16 x) { return __bfloat162float(x); }
DEV bf16  f2b(float x)      { return __float2bfloat16(x); }
DEV unsigned short f2bu(float x) { bf16 h = f2b(x); return *(unsigned short*)&h; }
DEV float bu2f(unsigned short u) { unsigned int t = ((unsigned int)u) << 16; return *(float*)&t; }
DEV float softplusf(float x){ return x > 20.f ? x : log1pf(expf(x)); }
DEV float geluf(float x) {
    float th = tanhf(0.7978845608028654f * (x + 0.044715f * x * x * x));
    return 0.5f * x * (1.f + th);
}

static constexpr int B_ = 2, T_ = 16, D_ = 64, HW = 4096;
static constexpr int NPIX = B_ * T_ * HW;               // 131072
static constexpr long long N1 = (long long)NPIX * 128;  // 16777216

// workspace offsets (floats). Total 50,505,792 floats = 192.7 MiB.
static constexpr long long BUFA  = 0;                   // x_eig f32 -> u_out (in-place)
static constexpr long long XUBF  = N1;                  // xupd bf16 (N1 ushort)
static constexpr long long DECBF = N1 + N1 / 2;         // decoded bf16
static constexpr long long XNBF  = 2 * N1;              // xn bf16 -> dn bf16
static constexpr long long XCBF  = 2 * N1 + N1 / 2;     // xc bf16 (orig x, ch-concat)
static constexpr long long XMEAN = 3 * N1;              // 4096 f32
static constexpr long long TABS  = XMEAN + 4096;        // 7 * 2048 f32
static constexpr long long FLAGO = TABS + 14336;        // 64
static constexpr long long WCP   = FLAGO + 64;          // conv w packed: 147456 ushort
static constexpr long long W1P   = WCP + 73728;         // 65536 ushort
static constexpr long long W2P   = W1P + 32768;         // 65536 ushort
static constexpr long long WEP   = W2P + 32768;         // 16384 ushort
static constexpr long long WDP   = WEP + 8192;          // 16384 ushort

// out offsets (elements)
static constexpr long long ZOUT = 0;
static constexpr long long HOUT = 16777216;
static constexpr long long FOUT = 17825792;

DEV float ld(const void* p, long long i, bool bf) {
    if (bf) return b2f(((const bf16*)p)[i]);
    return ((const float*)p)[i];
}

// ---- dtype detection --------------------------------------------------------
__global__ void k_detect(const unsigned short* __restrict__ x, float* __restrict__ ws) {
    int lane = threadIdx.x;
    int cnt = 0;
    for (int i = lane; i < 256; i += 64) {
        int e = (x[i] >> 7) & 0xFF;
        cnt += (e >= 100 && e <= 140) ? 1 : 0;
    }
    for (int m = 1; m < 64; m <<= 1) cnt += __shfl_xor(cnt, m, 64);
    if (lane == 0) ws[FLAGO] = (cnt >= 224) ? 1.f : 0.f;
}

// ---- weight pre-pack into MFMA B-fragment order -----------------------------
// B-frag: lane holds B[k = (lane>>4)*8 + j][n = lane&15], j=0..7 contiguous.
__global__ void k_convert(const void* Wc, const void* W1, const void* W2,
                          const void* Er, const void* Ei, const void* Dr, const void* Di,
                          float* ws) {
    bool bf = ws[FLAGO] != 0.f;
    int i = blockIdx.x * 256 + threadIdx.x;
    unsigned short* wcp = (unsigned short*)(ws + WCP);
    unsigned short* w1p = (unsigned short*)(ws + W1P);
    unsigned short* w2p = (unsigned short*)(ws + W2P);
    unsigned short* wep = (unsigned short*)(ws + WEP);
    unsigned short* wdp = (unsigned short*)(ws + WDP);
    if (i < 147456) {   // conv: [tap][kc(4)][nt(8)][lane][j]
        int j = i & 7, lane = (i >> 3) & 63, nt = (i >> 9) & 7, kc = (i >> 12) & 3, tap = i >> 14;
        int ic = kc * 32 + ((lane >> 4) << 3) + j, oc = nt * 16 + (lane & 15);
        wcp[i] = f2bu(ld(Wc, tap * 16384 + ic * 128 + oc, bf)); return;
    } i -= 147456;
    if (i < 65536) {    // W1 (128x512): [kc(4)][nt(32)][lane][j]
        int j = i & 7, lane = (i >> 3) & 63, nt = (i >> 9) & 31, kc = i >> 14;
        int ic = kc * 32 + ((lane >> 4) << 3) + j, oc = nt * 16 + (lane & 15);
        w1p[i] = f2bu(ld(W1, ic * 512 + oc, bf)); return;
    } i -= 65536;
    if (i < 65536) {    // W2 (512x128): [kc(16)][nt(8)][lane][j]
        int j = i & 7, lane = (i >> 3) & 63, nt = (i >> 9) & 7, kc = i >> 12;
        int ic = kc * 32 + ((lane >> 4) << 3) + j, oc = nt * 16 + (lane & 15);
        w2p[i] = f2bu(ld(W2, ic * 128 + oc, bf)); return;
    } i -= 65536;
    if (i < 16384) {    // WE = [[Er,Ei],[-Ei,Er]] (128x128): [kc(4)][nt(8)][lane][j]
        int j = i & 7, lane = (i >> 3) & 63, nt = (i >> 9) & 7, kc = i >> 12;
        int k = kc * 32 + ((lane >> 4) << 3) + j, n = nt * 16 + (lane & 15);
        float v;
        if (k < 64) v = (n < 64) ? ld(Er, k * 64 + n, bf) : ld(Ei, k * 64 + (n - 64), bf);
        else        v = (n < 64) ? -ld(Ei, (k - 64) * 64 + n, bf) : ld(Er, (k - 64) * 64 + (n - 64), bf);
        wep[i] = f2bu(v); return;
    } i -= 16384;
    if (i < 16384) {    // WD from Dec
        int j = i & 7, lane = (i >> 3) & 63, nt = (i >> 9) & 7, kc = i >> 12;
        int k = kc * 32 + ((lane >> 4) << 3) + j, n = nt * 16 + (lane & 15);
        float v;
        if (k < 64) v = (n < 64) ? ld(Dr, k * 64 + n, bf) : ld(Di, k * 64 + (n - 64), bf);
        else        v = (n < 64) ? -ld(Di, (k - 64) * 64 + n, bf) : ld(Dr, (k - 64) * 64 + (n - 64), bf);
        wdp[i] = f2bu(v); return;
    }
}

// ---- stage A: moveaxis + LN -> xc_bf, xn_bf (bf16) --------------------------
// block: one (b,t) x 64-pixel group. D rows 0..63 of re and im.
__global__ __launch_bounds__(256) void kA_ln(const void* __restrict__ xre,
                                             const void* __restrict__ xim,
                                             const void* __restrict__ gs,
                                             const void* __restrict__ bs,
                                             float* __restrict__ ws) {
    __shared__ unsigned short sr[64][72] __attribute__((aligned(16)));
    __shared__ unsigned short si[64][72] __attribute__((aligned(16)));
    __shared__ float red[2][4][64];
    __shared__ float mv[64], rv[64], gb[256];
    bool bf = ws[FLAGO] != 0.f;
    int blk = blockIdx.x;
    int bt = blk >> 6;                 // 0..31
    int px0 = (blk & 63) * 64;         // pixel group within image
    int tid = threadIdx.x;
    gb[tid] = (tid < 128) ? ld(gs, tid, bf) : ld(bs, tid - 128, bf);
    if (bf) {
        const unsigned short* xr16 = (const unsigned short*)xre;
        const unsigned short* xi16 = (const unsigned short*)xim;
        for (int l = tid; l < 1024; l += 256) {     // 2 arrays x 64 d x 8 chunks
            int a = l >> 9, dd = (l >> 3) & 63, ck = l & 7;
            long long src = (long long)bt * 262144 + (long long)dd * 4096 + px0 + ck * 8;
            bhalf8 v = *(const bhalf8*)&(a ? xi16 : xr16)[src];
            *(bhalf8*)&(a ? si : sr)[dd][ck * 8] = v;
        }
    } else {
        for (int l = tid; l < 8192; l += 256) {     // 2 arrays x 64 d x 64 px
            int a = l >> 12, dd = (l >> 6) & 63, px = l & 63;
            float v = ((const float*)(a ? xim : xre))[(long long)bt * 262144 + (long long)dd * 4096 + px0 + px];
            (a ? si : sr)[dd][px] = f2bu(v);
        }
    }
    __syncthreads();
    int px = tid & 63, part = tid >> 6;
    float s = 0.f, ss = 0.f;
    for (int d = part * 16; d < part * 16 + 16; d++) {
        float r = bu2f(sr[d][px]), q = bu2f(si[d][px]);
        s += r + q; ss += r * r + q * q;
    }
    red[0][part][px] = s; red[1][part][px] = ss;
    __syncthreads();
    if (tid < 64) {
        float S  = red[0][0][tid] + red[0][1][tid] + red[0][2][tid] + red[0][3][tid];
        float SS = red[1][0][tid] + red[1][1][tid] + red[1][2][tid] + red[1][3][tid];
        float m = S * (1.f / 128.f);
        mv[tid] = m;
        rv[tid] = rsqrtf(SS * (1.f / 128.f) - m * m + 1e-5f);
    }
    __syncthreads();
    unsigned short* xcb = (unsigned short*)(ws + XCBF);
    unsigned short* xnb = (unsigned short*)(ws + XNBF);
    long long pbase = ((long long)bt * 4096 + px0) * 128;
    for (int l = tid; l < 8192; l += 256) {
        int p2 = l >> 7, ch = l & 127, d = ch & 63;
        unsigned short raw = (ch < 64 ? sr : si)[d][p2];
        float v = bu2f(raw);
        xcb[pbase + p2 * 128 + ch] = raw;
        xnb[pbase + p2 * 128 + ch] = f2bu((v - mv[p2]) * rv[p2] * gb[ch] + gb[128 + ch]);
    }
}

// ---- stage B: 3x3 conv 128->128 MFMA implicit GEMM, + x + bc -> xupd bf16 ---
__global__ __launch_bounds__(256) void kB_conv(const void* __restrict__ bc,
                                               float* __restrict__ ws) {
    __shared__ unsigned short xt[3][64][136] __attribute__((aligned(16)));
    bool bf = ws[FLAGO] != 0.f;
    int blk = blockIdx.x, bt = blk >> 6, h = blk & 63;
    int tid = threadIdx.x, lane = tid & 63, wv = tid >> 6;
    int m16 = lane & 15, quad = lane >> 4;
    const unsigned short* xnb = (const unsigned short*)(ws + XNBF);
    const unsigned short* wcp = (const unsigned short*)(ws + WCP);
    bhalf8 zero8 = {0, 0, 0, 0, 0, 0, 0, 0};
    for (int l = tid; l < 3072; l += 256) {   // 3 rows x 64 cols x 16 chunks
        int r = l >> 10, rem = l & 1023, col = rem >> 4, ck = rem & 15;
        int hr = h - 1 + r;
        bhalf8 v = zero8;
        if (hr >= 0 && hr < 64)
            v = *(const bhalf8*)&xnb[(((long long)bt * 4096 + hr * 64 + col) << 7) + ck * 8];
        *(bhalf8*)&xt[r][col][ck * 8] = v;
    }
    __syncthreads();
    floatx4 acc[4][2];
    #pragma unroll
    for (int mt = 0; mt < 4; mt++)
        #pragma unroll
        for (int nt = 0; nt < 2; nt++)
            acc[mt][nt] = (floatx4){0.f, 0.f, 0.f, 0.f};
    for (int tap = 0; tap < 9; tap++) {
        int dy = tap / 3, dx = tap - dy * 3;
        #pragma unroll
        for (int kc = 0; kc < 4; kc++) {
            bhalf8 bfr[2];
            #pragma unroll
            for (int nt = 0; nt < 2; nt++)
                bfr[nt] = *(const bhalf8*)&wcp[((((tap * 4 + kc) * 8) + (wv * 2 + nt)) * 64 + lane) * 8];
            #pragma unroll
            for (int mt = 0; mt < 4; mt++) {
                int col = mt * 16 + m16 + dx - 1;
                bhalf8 af = zero8;
                if (col >= 0 && col < 64)
                    af = *(const bhalf8*)&xt[dy][col][kc * 32 + quad * 8];
                acc[mt][0] = __builtin_amdgcn_mfma_f32_16x16x32_bf16(af, bfr[0], acc[mt][0], 0, 0, 0);
                acc[mt][1] = __builtin_amdgcn_mfma_f32_16x16x32_bf16(af, bfr[1], acc[mt][1], 0, 0, 0);
            }
        }
    }
    const unsigned short* xcb = (const unsigned short*)(ws + XCBF);
    unsigned short* xub = (unsigned short*)(ws + XUBF);
    #pragma unroll
    for (int nt = 0; nt < 2; nt++) {
        int n = wv * 32 + nt * 16 + m16;
        float bcv = ld(bc, n, bf);
        #pragma unroll
        for (int mt = 0; mt < 4; mt++)
            #pragma unroll
            for (int r = 0; r < 4; r++) {
                int m = mt * 16 + quad * 4 + r;
                long long p = (long long)bt * 4096 + h * 64 + m;
                xub[p * 128 + n] = f2bu(acc[mt][nt][r] + bu2f(xcb[p * 128 + n]) + bcv);
            }
    }
}

// ---- stage C: x_eig = xupd @ WE (MFMA) -> BUFA f32, + x_mean atomics --------
__global__ __launch_bounds__(256) void kC_eig(float* __restrict__ ws) {
    __shared__ unsigned short At[64][136] __attribute__((aligned(16)));
    int blk = blockIdx.x, bt = blk >> 6;
    long long px0 = (long long)blk * 64;
    int tid = threadIdx.x, lane = tid & 63, wv = tid >> 6;
    int m16 = lane & 15, quad = lane >> 4;
    const unsigned short* xub = (const unsigned short*)(ws + XUBF);
    for (int l = tid; l < 1024; l += 256) {   // 64 px x 16 chunks
        int p2 = l >> 4, ck = l & 15;
        *(bhalf8*)&At[p2][ck * 8] = *(const bhalf8*)&xub[(px0 + p2) * 128 + ck * 8];
    }
    __syncthreads();
    const unsigned short* wep = (const unsigned short*)(ws + WEP);
    floatx4 acc[4][2];
    #pragma unroll
    for (int mt = 0; mt < 4; mt++)
        #pragma unroll
        for (int nt = 0; nt < 2; nt++)
            acc[mt][nt] = (floatx4){0.f, 0.f, 0.f, 0.f};
    #pragma unroll
    for (int kc = 0; kc < 4; kc++) {
        bhalf8 bfr[2];
        #pragma unroll
        for (int nt = 0; nt < 2; nt++)
            bfr[nt] = *(const bhalf8*)&wep[(((kc * 8) + wv * 2 + nt) * 64 + lane) * 8];
        #pragma unroll
        for (int mt = 0; mt < 4; mt++) {
            bhalf8 af = *(const bhalf8*)&At[mt * 16 + m16][kc * 32 + quad * 8];
            acc[mt][0] = __builtin_amdgcn_mfma_f32_16x16x32_bf16(af, bfr[0], acc[mt][0], 0, 0, 0);
            acc[mt][1] = __builtin_amdgcn_mfma_f32_16x16x32_bf16(af, bfr[1], acc[mt][1], 0, 0, 0);
        }
    }
    #pragma unroll
    for (int nt = 0; nt < 2; nt++) {
        int n = wv * 32 + nt * 16 + m16;
        float part = 0.f;
        #pragma unroll
        for (int mt = 0; mt < 4; mt++)
            #pragma unroll
            for (int r = 0; r < 4; r++) {
                int m = mt * 16 + quad * 4 + r;
                ws[BUFA + (px0 + m) * 128 + n] = acc[mt][nt][r];
                part += acc[mt][nt][r];
            }
        part += __shfl_xor(part, 16, 64);
        part += __shfl_xor(part, 32, 64);
        if (quad == 0) atomicAdd(ws + XMEAN + bt * 128 + n, part);
    }
}

// ---- stage D: flux recurrence, source, gate, op tables, flux_out ------------
__global__ __launch_bounds__(256) void kD_flux(const void* __restrict__ fxr, const void* __restrict__ fxi,
                                               const void* __restrict__ dtseq, const void* __restrict__ lamflux,
                                               const void* __restrict__ Wsr, const void* __restrict__ Wsi,
                                               const void* __restrict__ wgate, const void* __restrict__ bgate,
                                               const void* __restrict__ lamreraw, const void* __restrict__ lamim,
                                               float* __restrict__ ws, void* __restrict__ outv) {
    bool bfo = ws[FLAGO] != 0.f;
    int b = blockIdx.x;
    int tid = threadIdx.x;
    int d = tid & 63, g = tid >> 6;
    __shared__ float fr[64], fi[64], psr[4][64], psi[4][64];
    float lam_f = softplusf(ld(lamflux, d, bfo));
    float lre = -softplusf(ld(lamreraw, d, bfo));
    float lim = ld(lamim, d, bfo);
    float cr = 0.f, ci = 0.f;
    if (g == 0) { cr = ld(fxr, b * 64 + d, bfo); ci = ld(fxi, b * 64 + d, bfo); }
    float* tabs = ws + TABS;
    const float* xmean = ws + XMEAN;
    for (int t = 0; t < 16; t++) {
        float dt = ld(dtseq, b * 16 + t, bfo);
        int idx = b * 1024 + t * 64 + d;
        if (g == 0) {
            float A = expf(-lam_f * dt);
            float xr = xmean[(b * 16 + t) * 128 + d]      * (1.f / 4096.f) * dt;
            float xq = xmean[(b * 16 + t) * 128 + 64 + d] * (1.f / 4096.f) * dt;
            cr = A * cr + xr; ci = A * ci + xq;
            fr[d] = cr; fi[d] = ci;
        }
        __syncthreads();
        {
            float pr = 0.f, pi = 0.f;
            #pragma unroll
            for (int k = 0; k < 16; k++) {
                int d2 = g * 16 + k;
                float wr = ld(Wsr, d2 * 64 + d, bfo), wi = ld(Wsi, d2 * 64 + d, bfo);
                pr += fr[d2] * wr - fi[d2] * wi;
                pi += fr[d2] * wi + fi[d2] * wr;
            }
            psr[g][d] = pr; psi[g][d] = pi;
        }
        if (g == 1) {
            float od  = expf(lre * dt);
            float odr = od * cosf(lim * dt);
            float odi = od * sinf(lim * dt);
            tabs[3 * 2048 + idx] = odr; tabs[4 * 2048 + idx] = odi;
            float den = lre * lre + lim * lim;
            float tr = odr - 1.f;
            tabs[5 * 2048 + idx] = (tr * lre + odi * lim) / den;
            tabs[6 * 2048 + idx] = (odi * lre - tr * lim) / den;
        }
        __syncthreads();
        if (g == 0) {
            float sr = psr[0][d] + psr[1][d] + psr[2][d] + psr[3][d];
            float si2 = psi[0][d] + psi[1][d] + psi[2][d] + psi[3][d];
            tabs[1 * 2048 + idx] = sr; tabs[2 * 2048 + idx] = si2;
            tabs[0 * 2048 + idx] = 1.f / (1.f + expf(-(cr * ld(wgate, d, bfo) + ld(bgate, d, bfo))));
            if (t == 15) {
                if (bfo) {
                    bf16* ob = (bf16*)outv;
                    ob[FOUT + (b * 64 + d) * 2]     = f2b(cr);
                    ob[FOUT + (b * 64 + d) * 2 + 1] = f2b(ci);
                } else {
                    float* of = (float*)outv;
                    of[FOUT + (b * 64 + d) * 2]     = cr;
                    of[FOUT + (b * 64 + d) * 2 + 1] = ci;
                }
            }
        }
    }
}

// ---- stage E: per-(b,h,w,d) time recurrence, u_out (in-place) + h_out -------
__global__ __launch_bounds__(256) void kE_scan(const void* __restrict__ hre,
                                               const void* __restrict__ him,
                                               float* __restrict__ ws, void* __restrict__ outv) {
    __shared__ float tab[7][16][64];
    bool bfo = ws[FLAGO] != 0.f;
    long long G = (long long)blockIdx.x * 256 + threadIdx.x;
    int d = threadIdx.x & 63;
    int pix = (int)((G >> 6) & 4095);
    int b = (int)(G >> 18);
    const float* tabs = ws + TABS;
    for (int l = threadIdx.x; l < 7 * 1024; l += 256) {
        int a = l >> 10, idx = l & 1023;
        ((float*)tab)[l] = tabs[a * 2048 + b * 1024 + idx];
    }
    __syncthreads();
    long long hidx = ((long long)b * 4096 + pix) * 64 + d;
    float cr = ld(hre, hidx, bfo), ci = ld(him, hidx, bfo);
    float* xe = ws + BUFA;
    for (int t = 0; t < 16; t++) {
        long long base = ((long long)((b * 16 + t) * 4096 + pix)) * 128 + d;
        float xr = xe[base], xi = xe[base + 64];
        float gt = tab[0][t][d], sr = tab[1][t][d], si = tab[2][t][d];
        float odr = tab[3][t][d], odi = tab[4][t][d];
        float ofr = tab[5][t][d], ofi = tab[6][t][d];
        float fre = xr * gt + sr * (1.f - gt);
        float fim = xi * gt + si * (1.f - gt);
        float ure = fre * ofr - fim * ofi;
        float uim = fre * ofi + fim * ofr;
        float ncr = odr * cr - odi * ci + ure;
        float nci = odr * ci + odi * cr + uim;
        cr = ncr; ci = nci;
        xe[base] = cr; xe[base + 64] = ci;
    }
    if (bfo) {
        __hip_bfloat162 hv; hv.x = f2b(cr); hv.y = f2b(ci);
        ((__hip_bfloat162*)((bf16*)outv + HOUT))[hidx] = hv;
    } else {
        float2 hv; hv.x = cr; hv.y = ci;
        ((float2*)((float*)outv + HOUT))[hidx] = hv;
    }
}

// ---- stage F1: decoded = u_out @ WD (MFMA) -> DECBF bf16, LN -> dn bf16 -----
__global__ __launch_bounds__(256) void kF1_dec(const void* __restrict__ gt_,
                                               const void* __restrict__ bt_,
                                               float* __restrict__ ws) {
    __shared__ unsigned short At[64][136] __attribute__((aligned(16)));
    __shared__ float Ct[64][132];
    __shared__ float mv[64], rv[64], gbt[256];
    bool bf = ws[FLAGO] != 0.f;
    long long px0 = (long long)blockIdx.x * 64;
    int tid = threadIdx.x, lane = tid & 63, wv = tid >> 6;
    int m16 = lane & 15, quad = lane >> 4;
    gbt[tid] = (tid < 128) ? ld(gt_, tid, bf) : ld(bt_, tid - 128, bf);
    const float* uo = ws + BUFA + px0 * 128;
    for (int l = tid; l < 2048; l += 256) {
        int p2 = l >> 5, c4 = (l & 31) * 4;
        float4 v = *(const float4*)&uo[p2 * 128 + c4];
        unsigned short* dst = &At[p2][c4];
        dst[0] = f2bu(v.x); dst[1] = f2bu(v.y); dst[2] = f2bu(v.z); dst[3] = f2bu(v.w);
    }
    __syncthreads();
    const unsigned short* wdp = (const unsigned short*)(ws + WDP);
    floatx4 acc[4][2];
    #pragma unroll
    for (int mt = 0; mt < 4; mt++)
        #pragma unroll
        for (int nt = 0; nt < 2; nt++)
            acc[mt][nt] = (floatx4){0.f, 0.f, 0.f, 0.f};
    #pragma unroll
    for (int kc = 0; kc < 4; kc++) {
        bhalf8 bfr[2];
        #pragma unroll
        for (int nt = 0; nt < 2; nt++)
            bfr[nt] = *(const bhalf8*)&wdp[(((kc * 8) + wv * 2 + nt) * 64 + lane) * 8];
        #pragma unroll
        for (int mt = 0; mt < 4; mt++) {
            bhalf8 af = *(const bhalf8*)&At[mt * 16 + m16][kc * 32 + quad * 8];
            acc[mt][0] = __builtin_amdgcn_mfma_f32_16x16x32_bf16(af, bfr[0], acc[mt][0], 0, 0, 0);
            acc[mt][1] = __builtin_amdgcn_mfma_f32_16x16x32_bf16(af, bfr[1], acc[mt][1], 0, 0, 0);
        }
    }
    #pragma unroll
    for (int nt = 0; nt < 2; nt++) {
        int n = wv * 32 + nt * 16 + m16;
        #pragma unroll
        for (int mt = 0; mt < 4; mt++)
            #pragma unroll
            for (int r = 0; r < 4; r++)
                Ct[mt * 16 + quad * 4 + r][n] = acc[mt][nt][r];
    }
    __syncthreads();
    if (tid < 64) {
        float s = 0.f, ss = 0.f;
        for (int ch = 0; ch < 128; ch++) { float v = Ct[tid][ch]; s += v; ss += v * v; }
        float m = s * (1.f / 128.f);
        mv[tid] = m;
        rv[tid] = rsqrtf(ss * (1.f / 128.f) - m * m + 1e-5f);
    }
    __syncthreads();
    unsigned short* decb = (unsigned short*)(ws + DECBF);
    unsigned short* dnb  = (unsigned short*)(ws + XNBF);   // xn is dead
    for (int l = tid; l < 8192; l += 256) {
        int p2 = l >> 7, ch = l & 127;
        float v = Ct[p2][ch];
        decb[(px0 + p2) * 128 + ch] = f2bu(v);
        dnb [(px0 + p2) * 128 + ch] = f2bu((v - mv[p2]) * rv[p2] * gbt[ch] + gbt[128 + ch]);
    }
}

// ---- stage F2+F3 fused: MFMA MLP (128->512 gelu ->128) + z write ------------
__global__ __launch_bounds__(256) void kMLP(const void* __restrict__ b1v,
                                            const void* __restrict__ b2v,
                                            float* __restrict__ ws, void* __restrict__ outv) {
    __shared__ unsigned short A1[32][136] __attribute__((aligned(16)));
    __shared__ unsigned short h1[32][520] __attribute__((aligned(16)));
    bool bf = ws[FLAGO] != 0.f;
    long long px0 = (long long)blockIdx.x * 32;
    int tid = threadIdx.x, lane = tid & 63, wv = tid >> 6;
    int m16 = lane & 15, quad = lane >> 4;
    const unsigned short* dnb = (const unsigned short*)(ws + XNBF);
    for (int l = tid; l < 512; l += 256) {
        int p2 = l >> 4, ck = l & 15;
        *(bhalf8*)&A1[p2][ck * 8] = *(const bhalf8*)&dnb[(px0 + p2) * 128 + ck * 8];
    }
    __syncthreads();
    const unsigned short* w1p = (const unsigned short*)(ws + W1P);
    floatx4 acc1[2][8];
    #pragma unroll
    for (int mt = 0; mt < 2; mt++)
        #pragma unroll
        for (int nt = 0; nt < 8; nt++)
            acc1[mt][nt] = (floatx4){0.f, 0.f, 0.f, 0.f};
    #pragma unroll
    for (int kc = 0; kc < 4; kc++) {
        bhalf8 af0 = *(const bhalf8*)&A1[m16][kc * 32 + quad * 8];
        bhalf8 af1 = *(const bhalf8*)&A1[16 + m16][kc * 32 + quad * 8];
        #pragma unroll
        for (int nt = 0; nt < 8; nt++) {
            bhalf8 bfr = *(const bhalf8*)&w1p[(((kc * 32) + wv * 8 + nt) * 64 + lane) * 8];
            acc1[0][nt] = __builtin_amdgcn_mfma_f32_16x16x32_bf16(af0, bfr, acc1[0][nt], 0, 0, 0);
            acc1[1][nt] = __builtin_amdgcn_mfma_f32_16x16x32_bf16(af1, bfr, acc1[1][nt], 0, 0, 0);
        }
    }
    #pragma unroll
    for (int nt = 0; nt < 8; nt++) {
        int n = (wv * 8 + nt) * 16 + m16;
        float b1f = ld(b1v, n, bf);
        #pragma unroll
        for (int mt = 0; mt < 2; mt++)
            #pragma unroll
            for (int r = 0; r < 4; r++)
                h1[mt * 16 + quad * 4 + r][n] = f2bu(geluf(acc1[mt][nt][r] + b1f));
    }
    __syncthreads();
    const unsigned short* w2p = (const unsigned short*)(ws + W2P);
    floatx4 acc2[2][2];
    #pragma unroll
    for (int mt = 0; mt < 2; mt++)
        #pragma unroll
        for (int nt = 0; nt < 2; nt++)
            acc2[mt][nt] = (floatx4){0.f, 0.f, 0.f, 0.f};
    for (int kc = 0; kc < 16; kc++) {
        bhalf8 af0 = *(const bhalf8*)&h1[m16][kc * 32 + quad * 8];
        bhalf8 af1 = *(const bhalf8*)&h1[16 + m16][kc * 32 + quad * 8];
        #pragma unroll
        for (int nt = 0; nt < 2; nt++) {
            bhalf8 bfr = *(const bhalf8*)&w2p[(((kc * 8) + wv * 2 + nt) * 64 + lane) * 8];
            acc2[0][nt] = __builtin_amdgcn_mfma_f32_16x16x32_bf16(af0, bfr, acc2[0][nt], 0, 0, 0);
            acc2[1][nt] = __builtin_amdgcn_mfma_f32_16x16x32_bf16(af1, bfr, acc2[1][nt], 0, 0, 0);
        }
    }
    const unsigned short* decb = (const unsigned short*)(ws + DECBF);
    const unsigned short* xub  = (const unsigned short*)(ws + XUBF);
    #pragma unroll
    for (int nt = 0; nt < 2; nt++) {
        int n = wv * 32 + nt * 16 + m16;
        float b2f_ = ld(b2v, n, bf);
        #pragma unroll
        for (int mt = 0; mt < 2; mt++)
            #pragma unroll
            for (int r = 0; r < 4; r++) {
                long long p = px0 + mt * 16 + quad * 4 + r;
                float val = acc2[mt][nt][r] + b2f_ + bu2f(xub[p * 128 + n]) + bu2f(decb[p * 128 + n]);
                long long oidx = p * 128 + ((n < 64) ? (2 * n) : (2 * (n - 64) + 1));
                if (bf) ((bf16*)outv)[ZOUT + oidx] = f2b(val);
                else    ((float*)outv)[ZOUT + oidx] = val;
            }
    }
}

extern "C" void kernel_launch(void* const* d_in, const int* in_sizes, int n_in,
                              void* d_out, int out_size, void* d_ws, size_t ws_size,
                              hipStream_t stream) {
    const void* x_re  = d_in[0];
    const void* x_im  = d_in[1];
    const void* h_re  = d_in[2];
    const void* h_im  = d_in[3];
    const void* fl_re = d_in[4];
    const void* fl_im = d_in[5];
    const void* dtseq = d_in[6];
    const void* g_s   = d_in[7];
    const void* b_s   = d_in[8];
    const void* Wc    = d_in[9];
    const void* bc    = d_in[10];
    const void* g_t   = d_in[11];
    const void* b_t   = d_in[12];
    const void* E_re  = d_in[13];
    const void* E_im  = d_in[14];
    const void* De_re = d_in[15];
    const void* De_im = d_in[16];
    const void* lamfl = d_in[17];
    const void* Ws_re = d_in[18];
    const void* Ws_im = d_in[19];
    const void* wgate = d_in[20];
    const void* bgate = d_in[21];
    const void* lamrr = d_in[22];
    const void* lamim = d_in[23];
    const void* W1    = d_in[24];
    const void* b1    = d_in[25];
    const void* W2    = d_in[26];
    const void* b2    = d_in[27];
    float* ws = (float*)d_ws;

    hipMemsetAsync((char*)d_ws + XMEAN * sizeof(float), 0, 4096 * sizeof(float), stream);
    k_detect<<<1, 64, 0, stream>>>((const unsigned short*)x_re, ws);
    k_convert<<<1216, 256, 0, stream>>>(Wc, W1, W2, E_re, E_im, De_re, De_im, ws);
    kA_ln<<<2048, 256, 0, stream>>>(x_re, x_im, g_s, b_s, ws);
    kB_conv<<<2048, 256, 0, stream>>>(bc, ws);
    kC_eig<<<2048, 256, 0, stream>>>(ws);
    kD_flux<<<2, 256, 0, stream>>>(fl_re, fl_im, dtseq, lamfl, Ws_re, Ws_im,
                                   wgate, bgate, lamrr, lamim, ws, d_out);
    kE_scan<<<2048, 256, 0, stream>>>(h_re, h_im, ws, d_out);
    kF1_dec<<<2048, 256, 0, stream>>>(g_t, b_t, ws);
    kMLP<<<4096, 256, 0, stream>>>(b1, b2, ws, d_out);
}

// Round 6
// 455.232 us; speedup vs baseline: 15.6457x; 1.1253x over previous
//
#include <hip/hip_runtime.h>
#include <hip/hip_bf16.h>

// UniPhyBlock: B=2,T=16,D=64,H=64,W=64. Outputs bf16; internal f32 accum,
// bf16 MFMA for conv / eig / dec / MLP. Input dtype auto-detected.
// Pipeline: detect -> convert(pack) -> kA(LN, bf16 out) -> kB(conv3x3 MFMA)
//   -> kC(eig MFMA + mean, bf16 out) -> kD(flux scan) -> kE(scan, bf16 u_out)
//   -> kF1(dec MFMA + LN) -> kMLP(MFMA MLP, fast gelu, vector epilogue)
// Workspace 192.7 MiB.

typedef __hip_bfloat16 bf16;
typedef __attribute__((ext_vector_type(8))) short bhalf8;   // 8 bf16 (4 VGPR)
typedef __attribute__((ext_vector_type(4))) float floatx4;  // MFMA C/D

#define DEV __device__ __forceinline__

DEV float b2f(const bf16 x) { return __bfloat162float(x); }
DEV bf16  f2b(float x)      { return __float2bfloat16(x); }
DEV unsigned short f2bu(float x) { bf16 h = f2b(x); return *(unsigned short*)&h; }
DEV float bu2f(unsigned short u) { unsigned int t = ((unsigned int)u) << 16; return *(float*)&t; }
DEV float softplusf(float x){ return x > 20.f ? x : log1pf(expf(x)); }
// gelu(x) = x * sigmoid(x*(a + b x^2)), a=2*0.7978845608, b=a*0.044715
DEV float geluf(float x) {
    float v = x * fmaf(x * x, 0.0713548162726f, 1.5957691216057308f);
    float e = __expf(-v);
    return x * __builtin_amdgcn_rcpf(1.f + e);
}

static constexpr int B_ = 2, T_ = 16, D_ = 64, HW = 4096;
static constexpr int NPIX = B_ * T_ * HW;               // 131072
static constexpr long long N1 = (long long)NPIX * 128;  // 16777216

// workspace offsets (floats). Total 50,505,792 floats = 192.7 MiB.
static constexpr long long BUFA  = 0;                   // x_eig bf16 (N1 ushort)
static constexpr long long XUBF  = N1;                  // xupd bf16 (N1 ushort)
static constexpr long long DECBF = N1 + N1 / 2;         // decoded bf16
static constexpr long long XNBF  = 2 * N1;              // xn bf16 -> dn bf16
static constexpr long long XCBF  = 2 * N1 + N1 / 2;     // xc bf16 -> u_out bf16
static constexpr long long XMEAN = 3 * N1;              // 4096 f32
static constexpr long long TABS  = XMEAN + 4096;        // 7 * 2048 f32
static constexpr long long FLAGO = TABS + 14336;        // 64
static constexpr long long WCP   = FLAGO + 64;          // conv w packed: 147456 ushort
static constexpr long long W1P   = WCP + 73728;         // 65536 ushort
static constexpr long long W2P   = W1P + 32768;         // 65536 ushort
static constexpr long long WEP   = W2P + 32768;         // 16384 ushort
static constexpr long long WDP   = WEP + 8192;          // 16384 ushort

// out offsets (elements)
static constexpr long long ZOUT = 0;
static constexpr long long HOUT = 16777216;
static constexpr long long FOUT = 17825792;

DEV float ld(const void* p, long long i, bool bf) {
    if (bf) return b2f(((const bf16*)p)[i]);
    return ((const float*)p)[i];
}

// ---- dtype detection --------------------------------------------------------
__global__ void k_detect(const unsigned short* __restrict__ x, float* __restrict__ ws) {
    int lane = threadIdx.x;
    int cnt = 0;
    for (int i = lane; i < 256; i += 64) {
        int e = (x[i] >> 7) & 0xFF;
        cnt += (e >= 100 && e <= 140) ? 1 : 0;
    }
    for (int m = 1; m < 64; m <<= 1) cnt += __shfl_xor(cnt, m, 64);
    if (lane == 0) ws[FLAGO] = (cnt >= 224) ? 1.f : 0.f;
}

// ---- weight pre-pack into MFMA B-fragment order -----------------------------
// B-frag: lane holds B[k = (lane>>4)*8 + j][n = lane&15], j=0..7 contiguous.
__global__ void k_convert(const void* Wc, const void* W1, const void* W2,
                          const void* Er, const void* Ei, const void* Dr, const void* Di,
                          float* ws) {
    bool bf = ws[FLAGO] != 0.f;
    int i = blockIdx.x * 256 + threadIdx.x;
    unsigned short* wcp = (unsigned short*)(ws + WCP);
    unsigned short* w1p = (unsigned short*)(ws + W1P);
    unsigned short* w2p = (unsigned short*)(ws + W2P);
    unsigned short* wep = (unsigned short*)(ws + WEP);
    unsigned short* wdp = (unsigned short*)(ws + WDP);
    if (i < 147456) {   // conv: [tap][kc(4)][nt(8)][lane][j]
        int j = i & 7, lane = (i >> 3) & 63, nt = (i >> 9) & 7, kc = (i >> 12) & 3, tap = i >> 14;
        int ic = kc * 32 + ((lane >> 4) << 3) + j, oc = nt * 16 + (lane & 15);
        wcp[i] = f2bu(ld(Wc, tap * 16384 + ic * 128 + oc, bf)); return;
    } i -= 147456;
    if (i < 65536) {    // W1 (128x512): [kc(4)][nt(32)][lane][j]
        int j = i & 7, lane = (i >> 3) & 63, nt = (i >> 9) & 31, kc = i >> 14;
        int ic = kc * 32 + ((lane >> 4) << 3) + j, oc = nt * 16 + (lane & 15);
        w1p[i] = f2bu(ld(W1, ic * 512 + oc, bf)); return;
    } i -= 65536;
    if (i < 65536) {    // W2 (512x128): [kc(16)][nt(8)][lane][j]
        int j = i & 7, lane = (i >> 3) & 63, nt = (i >> 9) & 7, kc = i >> 12;
        int ic = kc * 32 + ((lane >> 4) << 3) + j, oc = nt * 16 + (lane & 15);
        w2p[i] = f2bu(ld(W2, ic * 128 + oc, bf)); return;
    } i -= 65536;
    if (i < 16384) {    // WE = [[Er,Ei],[-Ei,Er]] (128x128): [kc(4)][nt(8)][lane][j]
        int j = i & 7, lane = (i >> 3) & 63, nt = (i >> 9) & 7, kc = i >> 12;
        int k = kc * 32 + ((lane >> 4) << 3) + j, n = nt * 16 + (lane & 15);
        float v;
        if (k < 64) v = (n < 64) ? ld(Er, k * 64 + n, bf) : ld(Ei, k * 64 + (n - 64), bf);
        else        v = (n < 64) ? -ld(Ei, (k - 64) * 64 + n, bf) : ld(Er, (k - 64) * 64 + (n - 64), bf);
        wep[i] = f2bu(v); return;
    } i -= 16384;
    if (i < 16384) {    // WD from Dec
        int j = i & 7, lane = (i >> 3) & 63, nt = (i >> 9) & 7, kc = i >> 12;
        int k = kc * 32 + ((lane >> 4) << 3) + j, n = nt * 16 + (lane & 15);
        float v;
        if (k < 64) v = (n < 64) ? ld(Dr, k * 64 + n, bf) : ld(Di, k * 64 + (n - 64), bf);
        else        v = (n < 64) ? -ld(Di, (k - 64) * 64 + n, bf) : ld(Dr, (k - 64) * 64 + (n - 64), bf);
        wdp[i] = f2bu(v); return;
    }
}

// ---- stage A: moveaxis + LN -> xc_bf, xn_bf (bf16) --------------------------
__global__ __launch_bounds__(256) void kA_ln(const void* __restrict__ xre,
                                             const void* __restrict__ xim,
                                             const void* __restrict__ gs,
                                             const void* __restrict__ bs,
                                             float* __restrict__ ws) {
    __shared__ unsigned short sr[64][72] __attribute__((aligned(16)));
    __shared__ unsigned short si[64][72] __attribute__((aligned(16)));
    __shared__ float red[2][4][64];
    __shared__ float mv[64], rv[64], gb[256];
    bool bf = ws[FLAGO] != 0.f;
    int blk = blockIdx.x;
    int bt = blk >> 6;                 // 0..31
    int px0 = (blk & 63) * 64;         // pixel group within image
    int tid = threadIdx.x;
    gb[tid] = (tid < 128) ? ld(gs, tid, bf) : ld(bs, tid - 128, bf);
    if (bf) {
        const unsigned short* xr16 = (const unsigned short*)xre;
        const unsigned short* xi16 = (const unsigned short*)xim;
        for (int l = tid; l < 1024; l += 256) {     // 2 arrays x 64 d x 8 chunks
            int a = l >> 9, dd = (l >> 3) & 63, ck = l & 7;
            long long src = (long long)bt * 262144 + (long long)dd * 4096 + px0 + ck * 8;
            bhalf8 v = *(const bhalf8*)&(a ? xi16 : xr16)[src];
            *(bhalf8*)&(a ? si : sr)[dd][ck * 8] = v;
        }
    } else {
        for (int l = tid; l < 8192; l += 256) {     // 2 arrays x 64 d x 64 px
            int a = l >> 12, dd = (l >> 6) & 63, px = l & 63;
            float v = ((const float*)(a ? xim : xre))[(long long)bt * 262144 + (long long)dd * 4096 + px0 + px];
            (a ? si : sr)[dd][px] = f2bu(v);
        }
    }
    __syncthreads();
    int px = tid & 63, part = tid >> 6;
    float s = 0.f, ss = 0.f;
    for (int d = part * 16; d < part * 16 + 16; d++) {
        float r = bu2f(sr[d][px]), q = bu2f(si[d][px]);
        s += r + q; ss += r * r + q * q;
    }
    red[0][part][px] = s; red[1][part][px] = ss;
    __syncthreads();
    if (tid < 64) {
        float S  = red[0][0][tid] + red[0][1][tid] + red[0][2][tid] + red[0][3][tid];
        float SS = red[1][0][tid] + red[1][1][tid] + red[1][2][tid] + red[1][3][tid];
        float m = S * (1.f / 128.f);
        mv[tid] = m;
        rv[tid] = rsqrtf(SS * (1.f / 128.f) - m * m + 1e-5f);
    }
    __syncthreads();
    unsigned short* xcb = (unsigned short*)(ws + XCBF);
    unsigned short* xnb = (unsigned short*)(ws + XNBF);
    long long pbase = ((long long)bt * 4096 + px0) * 128;
    for (int l = tid; l < 8192; l += 256) {
        int p2 = l >> 7, ch = l & 127, d = ch & 63;
        unsigned short raw = (ch < 64 ? sr : si)[d][p2];
        float v = bu2f(raw);
        xcb[pbase + p2 * 128 + ch] = raw;
        xnb[pbase + p2 * 128 + ch] = f2bu((v - mv[p2]) * rv[p2] * gb[ch] + gb[128 + ch]);
    }
}

// ---- stage B: 3x3 conv 128->128 MFMA implicit GEMM, + x + bc -> xupd bf16 ---
__global__ __launch_bounds__(256) void kB_conv(const void* __restrict__ bc,
                                               float* __restrict__ ws) {
    __shared__ unsigned short xt[3][64][136] __attribute__((aligned(16)));
    bool bf = ws[FLAGO] != 0.f;
    int blk = blockIdx.x, bt = blk >> 6, h = blk & 63;
    int tid = threadIdx.x, lane = tid & 63, wv = tid >> 6;
    int m16 = lane & 15, quad = lane >> 4;
    const unsigned short* xnb = (const unsigned short*)(ws + XNBF);
    const unsigned short* wcp = (const unsigned short*)(ws + WCP);
    bhalf8 zero8 = {0, 0, 0, 0, 0, 0, 0, 0};
    for (int l = tid; l < 3072; l += 256) {   // 3 rows x 64 cols x 16 chunks
        int r = l >> 10, rem = l & 1023, col = rem >> 4, ck = rem & 15;
        int hr = h - 1 + r;
        bhalf8 v = zero8;
        if (hr >= 0 && hr < 64)
            v = *(const bhalf8*)&xnb[(((long long)bt * 4096 + hr * 64 + col) << 7) + ck * 8];
        *(bhalf8*)&xt[r][col][ck * 8] = v;
    }
    __syncthreads();
    floatx4 acc[4][2];
    #pragma unroll
    for (int mt = 0; mt < 4; mt++)
        #pragma unroll
        for (int nt = 0; nt < 2; nt++)
            acc[mt][nt] = (floatx4){0.f, 0.f, 0.f, 0.f};
    for (int tap = 0; tap < 9; tap++) {
        int dy = tap / 3, dx = tap - dy * 3;
        #pragma unroll
        for (int kc = 0; kc < 4; kc++) {
            bhalf8 bfr[2];
            #pragma unroll
            for (int nt = 0; nt < 2; nt++)
                bfr[nt] = *(const bhalf8*)&wcp[((((tap * 4 + kc) * 8) + (wv * 2 + nt)) * 64 + lane) * 8];
            #pragma unroll
            for (int mt = 0; mt < 4; mt++) {
                int col = mt * 16 + m16 + dx - 1;
                bhalf8 af = zero8;
                if (col >= 0 && col < 64)
                    af = *(const bhalf8*)&xt[dy][col][kc * 32 + quad * 8];
                acc[mt][0] = __builtin_amdgcn_mfma_f32_16x16x32_bf16(af, bfr[0], acc[mt][0], 0, 0, 0);
                acc[mt][1] = __builtin_amdgcn_mfma_f32_16x16x32_bf16(af, bfr[1], acc[mt][1], 0, 0, 0);
            }
        }
    }
    const unsigned short* xcb = (const unsigned short*)(ws + XCBF);
    unsigned short* xub = (unsigned short*)(ws + XUBF);
    #pragma unroll
    for (int nt = 0; nt < 2; nt++) {
        int n = wv * 32 + nt * 16 + m16;
        float bcv = ld(bc, n, bf);
        #pragma unroll
        for (int mt = 0; mt < 4; mt++)
            #pragma unroll
            for (int r = 0; r < 4; r++) {
                int m = mt * 16 + quad * 4 + r;
                long long p = (long long)bt * 4096 + h * 64 + m;
                xub[p * 128 + n] = f2bu(acc[mt][nt][r] + bu2f(xcb[p * 128 + n]) + bcv);
            }
    }
}

// ---- stage C: x_eig = xupd @ WE (MFMA) -> BUFA bf16, + x_mean atomics -------
__global__ __launch_bounds__(256) void kC_eig(float* __restrict__ ws) {
    __shared__ unsigned short At[64][136] __attribute__((aligned(16)));
    int blk = blockIdx.x, bt = blk >> 6;
    long long px0 = (long long)blk * 64;
    int tid = threadIdx.x, lane = tid & 63, wv = tid >> 6;
    int m16 = lane & 15, quad = lane >> 4;
    const unsigned short* xub = (const unsigned short*)(ws + XUBF);
    for (int l = tid; l < 1024; l += 256) {   // 64 px x 16 chunks
        int p2 = l >> 4, ck = l & 15;
        *(bhalf8*)&At[p2][ck * 8] = *(const bhalf8*)&xub[(px0 + p2) * 128 + ck * 8];
    }
    __syncthreads();
    const unsigned short* wep = (const unsigned short*)(ws + WEP);
    floatx4 acc[4][2];
    #pragma unroll
    for (int mt = 0; mt < 4; mt++)
        #pragma unroll
        for (int nt = 0; nt < 2; nt++)
            acc[mt][nt] = (floatx4){0.f, 0.f, 0.f, 0.f};
    #pragma unroll
    for (int kc = 0; kc < 4; kc++) {
        bhalf8 bfr[2];
        #pragma unroll
        for (int nt = 0; nt < 2; nt++)
            bfr[nt] = *(const bhalf8*)&wep[(((kc * 8) + wv * 2 + nt) * 64 + lane) * 8];
        #pragma unroll
        for (int mt = 0; mt < 4; mt++) {
            bhalf8 af = *(const bhalf8*)&At[mt * 16 + m16][kc * 32 + quad * 8];
            acc[mt][0] = __builtin_amdgcn_mfma_f32_16x16x32_bf16(af, bfr[0], acc[mt][0], 0, 0, 0);
            acc[mt][1] = __builtin_amdgcn_mfma_f32_16x16x32_bf16(af, bfr[1], acc[mt][1], 0, 0, 0);
        }
    }
    unsigned short* xeb = (unsigned short*)(ws + BUFA);
    #pragma unroll
    for (int nt = 0; nt < 2; nt++) {
        int n = wv * 32 + nt * 16 + m16;
        float part = 0.f;
        #pragma unroll
        for (int mt = 0; mt < 4; mt++)
            #pragma unroll
            for (int r = 0; r < 4; r++) {
                int m = mt * 16 + quad * 4 + r;
                xeb[(px0 + m) * 128 + n] = f2bu(acc[mt][nt][r]);
                part += acc[mt][nt][r];
            }
        part += __shfl_xor(part, 16, 64);
        part += __shfl_xor(part, 32, 64);
        if (quad == 0) atomicAdd(ws + XMEAN + bt * 128 + n, part);
    }
}

// ---- stage D: flux recurrence, source, gate, op tables, flux_out ------------
__global__ __launch_bounds__(256) void kD_flux(const void* __restrict__ fxr, const void* __restrict__ fxi,
                                               const void* __restrict__ dtseq, const void* __restrict__ lamflux,
                                               const void* __restrict__ Wsr, const void* __restrict__ Wsi,
                                               const void* __restrict__ wgate, const void* __restrict__ bgate,
                                               const void* __restrict__ lamreraw, const void* __restrict__ lamim,
                                               float* __restrict__ ws, void* __restrict__ outv) {
    bool bfo = ws[FLAGO] != 0.f;
    int b = blockIdx.x;
    int tid = threadIdx.x;
    int d = tid & 63, g = tid >> 6;
    __shared__ float fr[64], fi[64], psr[4][64], psi[4][64];
    float lam_f = softplusf(ld(lamflux, d, bfo));
    float lre = -softplusf(ld(lamreraw, d, bfo));
    float lim = ld(lamim, d, bfo);
    float cr = 0.f, ci = 0.f;
    if (g == 0) { cr = ld(fxr, b * 64 + d, bfo); ci = ld(fxi, b * 64 + d, bfo); }
    float* tabs = ws + TABS;
    const float* xmean = ws + XMEAN;
    for (int t = 0; t < 16; t++) {
        float dt = ld(dtseq, b * 16 + t, bfo);
        int idx = b * 1024 + t * 64 + d;
        if (g == 0) {
            float A = expf(-lam_f * dt);
            float xr = xmean[(b * 16 + t) * 128 + d]      * (1.f / 4096.f) * dt;
            float xq = xmean[(b * 16 + t) * 128 + 64 + d] * (1.f / 4096.f) * dt;
            cr = A * cr + xr; ci = A * ci + xq;
            fr[d] = cr; fi[d] = ci;
        }
        __syncthreads();
        {
            float pr = 0.f, pi = 0.f;
            #pragma unroll
            for (int k = 0; k < 16; k++) {
                int d2 = g * 16 + k;
                float wr = ld(Wsr, d2 * 64 + d, bfo), wi = ld(Wsi, d2 * 64 + d, bfo);
                pr += fr[d2] * wr - fi[d2] * wi;
                pi += fr[d2] * wi + fi[d2] * wr;
            }
            psr[g][d] = pr; psi[g][d] = pi;
        }
        if (g == 1) {
            float od  = expf(lre * dt);
            float odr = od * cosf(lim * dt);
            float odi = od * sinf(lim * dt);
            tabs[3 * 2048 + idx] = odr; tabs[4 * 2048 + idx] = odi;
            float den = lre * lre + lim * lim;
            float tr = odr - 1.f;
            tabs[5 * 2048 + idx] = (tr * lre + odi * lim) / den;
            tabs[6 * 2048 + idx] = (odi * lre - tr * lim) / den;
        }
        __syncthreads();
        if (g == 0) {
            float sr = psr[0][d] + psr[1][d] + psr[2][d] + psr[3][d];
            float si2 = psi[0][d] + psi[1][d] + psi[2][d] + psi[3][d];
            tabs[1 * 2048 + idx] = sr; tabs[2 * 2048 + idx] = si2;
            tabs[0 * 2048 + idx] = 1.f / (1.f + expf(-(cr * ld(wgate, d, bfo) + ld(bgate, d, bfo))));
            if (t == 15) {
                if (bfo) {
                    bf16* ob = (bf16*)outv;
                    ob[FOUT + (b * 64 + d) * 2]     = f2b(cr);
                    ob[FOUT + (b * 64 + d) * 2 + 1] = f2b(ci);
                } else {
                    float* of = (float*)outv;
                    of[FOUT + (b * 64 + d) * 2]     = cr;
                    of[FOUT + (b * 64 + d) * 2 + 1] = ci;
                }
            }
        }
    }
}

// ---- stage E: time recurrence; x_eig bf16 in BUFA -> u_out bf16 in XCBF -----
__global__ __launch_bounds__(256) void kE_scan(const void* __restrict__ hre,
                                               const void* __restrict__ him,
                                               float* __restrict__ ws, void* __restrict__ outv) {
    __shared__ float tab[7][16][64];
    bool bfo = ws[FLAGO] != 0.f;
    long long G = (long long)blockIdx.x * 256 + threadIdx.x;
    int d = threadIdx.x & 63;
    int pix = (int)((G >> 6) & 4095);
    int b = (int)(G >> 18);
    const float* tabs = ws + TABS;
    for (int l = threadIdx.x; l < 7 * 1024; l += 256) {
        int a = l >> 10, idx = l & 1023;
        ((float*)tab)[l] = tabs[a * 2048 + b * 1024 + idx];
    }
    __syncthreads();
    long long hidx = ((long long)b * 4096 + pix) * 64 + d;
    float cr = ld(hre, hidx, bfo), ci = ld(him, hidx, bfo);
    const unsigned short* xe = (const unsigned short*)(ws + BUFA);
    unsigned short* ub = (unsigned short*)(ws + XCBF);
    for (int t = 0; t < 16; t++) {
        long long base = ((long long)((b * 16 + t) * 4096 + pix)) * 128 + d;
        float xr = bu2f(xe[base]), xi = bu2f(xe[base + 64]);
        float gt = tab[0][t][d], sr = tab[1][t][d], si = tab[2][t][d];
        float odr = tab[3][t][d], odi = tab[4][t][d];
        float ofr = tab[5][t][d], ofi = tab[6][t][d];
        float fre = xr * gt + sr * (1.f - gt);
        float fim = xi * gt + si * (1.f - gt);
        float ure = fre * ofr - fim * ofi;
        float uim = fre * ofi + fim * ofr;
        float ncr = odr * cr - odi * ci + ure;
        float nci = odr * ci + odi * cr + uim;
        cr = ncr; ci = nci;
        ub[base] = f2bu(cr); ub[base + 64] = f2bu(ci);
    }
    if (bfo) {
        __hip_bfloat162 hv; hv.x = f2b(cr); hv.y = f2b(ci);
        ((__hip_bfloat162*)((bf16*)outv + HOUT))[hidx] = hv;
    } else {
        float2 hv; hv.x = cr; hv.y = ci;
        ((float2*)((float*)outv + HOUT))[hidx] = hv;
    }
}

// ---- stage F1: decoded = u_out(bf16) @ WD (MFMA) -> DECBF bf16, LN -> dn ----
__global__ __launch_bounds__(256) void kF1_dec(const void* __restrict__ gt_,
                                               const void* __restrict__ bt_,
                                               float* __restrict__ ws) {
    __shared__ unsigned short At[64][136] __attribute__((aligned(16)));
    __shared__ float Ct[64][132];
    __shared__ float mv[64], rv[64], gbt[256];
    bool bf = ws[FLAGO] != 0.f;
    long long px0 = (long long)blockIdx.x * 64;
    int tid = threadIdx.x, lane = tid & 63, wv = tid >> 6;
    int m16 = lane & 15, quad = lane >> 4;
    gbt[tid] = (tid < 128) ? ld(gt_, tid, bf) : ld(bt_, tid - 128, bf);
    const unsigned short* uo = (const unsigned short*)(ws + XCBF);
    for (int l = tid; l < 1024; l += 256) {
        int p2 = l >> 4, ck = l & 15;
        *(bhalf8*)&At[p2][ck * 8] = *(const bhalf8*)&uo[(px0 + p2) * 128 + ck * 8];
    }
    __syncthreads();
    const unsigned short* wdp = (const unsigned short*)(ws + WDP);
    floatx4 acc[4][2];
    #pragma unroll
    for (int mt = 0; mt < 4; mt++)
        #pragma unroll
        for (int nt = 0; nt < 2; nt++)
            acc[mt][nt] = (floatx4){0.f, 0.f, 0.f, 0.f};
    #pragma unroll
    for (int kc = 0; kc < 4; kc++) {
        bhalf8 bfr[2];
        #pragma unroll
        for (int nt = 0; nt < 2; nt++)
            bfr[nt] = *(const bhalf8*)&wdp[(((kc * 8) + wv * 2 + nt) * 64 + lane) * 8];
        #pragma unroll
        for (int mt = 0; mt < 4; mt++) {
            bhalf8 af = *(const bhalf8*)&At[mt * 16 + m16][kc * 32 + quad * 8];
            acc[mt][0] = __builtin_amdgcn_mfma_f32_16x16x32_bf16(af, bfr[0], acc[mt][0], 0, 0, 0);
            acc[mt][1] = __builtin_amdgcn_mfma_f32_16x16x32_bf16(af, bfr[1], acc[mt][1], 0, 0, 0);
        }
    }
    #pragma unroll
    for (int nt = 0; nt < 2; nt++) {
        int n = wv * 32 + nt * 16 + m16;
        #pragma unroll
        for (int mt = 0; mt < 4; mt++)
            #pragma unroll
            for (int r = 0; r < 4; r++)
                Ct[mt * 16 + quad * 4 + r][n] = acc[mt][nt][r];
    }
    __syncthreads();
    if (tid < 64) {
        float s = 0.f, ss = 0.f;
        for (int ch = 0; ch < 128; ch++) { float v = Ct[tid][ch]; s += v; ss += v * v; }
        float m = s * (1.f / 128.f);
        mv[tid] = m;
        rv[tid] = rsqrtf(ss * (1.f / 128.f) - m * m + 1e-5f);
    }
    __syncthreads();
    unsigned short* decb = (unsigned short*)(ws + DECBF);
    unsigned short* dnb  = (unsigned short*)(ws + XNBF);   // xn is dead
    for (int l = tid; l < 8192; l += 256) {
        int p2 = l >> 7, ch = l & 127;
        float v = Ct[p2][ch];
        decb[(px0 + p2) * 128 + ch] = f2bu(v);
        dnb [(px0 + p2) * 128 + ch] = f2bu((v - mv[p2]) * rv[p2] * gbt[ch] + gbt[128 + ch]);
    }
}

// ---- stage F2+F3 fused: MFMA MLP (128->512 gelu ->128) + vector z write -----
__global__ __launch_bounds__(256) void kMLP(const void* __restrict__ b1v,
                                            const void* __restrict__ b2v,
                                            float* __restrict__ ws, void* __restrict__ outv) {
    __shared__ unsigned short A1[32][136] __attribute__((aligned(16)));
    __shared__ unsigned short h1[32][520] __attribute__((aligned(16)));
    __shared__ float gb2[128];
    bool bf = ws[FLAGO] != 0.f;
    long long px0 = (long long)blockIdx.x * 32;
    int tid = threadIdx.x, lane = tid & 63, wv = tid >> 6;
    int m16 = lane & 15, quad = lane >> 4;
    const unsigned short* dnb = (const unsigned short*)(ws + XNBF);
    if (tid < 128) gb2[tid] = ld(b2v, tid, bf);
    for (int l = tid; l < 512; l += 256) {
        int p2 = l >> 4, ck = l & 15;
        *(bhalf8*)&A1[p2][ck * 8] = *(const bhalf8*)&dnb[(px0 + p2) * 128 + ck * 8];
    }
    __syncthreads();
    const unsigned short* w1p = (const unsigned short*)(ws + W1P);
    floatx4 acc1[2][8];
    #pragma unroll
    for (int mt = 0; mt < 2; mt++)
        #pragma unroll
        for (int nt = 0; nt < 8; nt++)
            acc1[mt][nt] = (floatx4){0.f, 0.f, 0.f, 0.f};
    #pragma unroll
    for (int kc = 0; kc < 4; kc++) {
        bhalf8 af0 = *(const bhalf8*)&A1[m16][kc * 32 + quad * 8];
        bhalf8 af1 = *(const bhalf8*)&A1[16 + m16][kc * 32 + quad * 8];
        #pragma unroll
        for (int nt = 0; nt < 8; nt++) {
            bhalf8 bfr = *(const bhalf8*)&w1p[(((kc * 32) + wv * 8 + nt) * 64 + lane) * 8];
            acc1[0][nt] = __builtin_amdgcn_mfma_f32_16x16x32_bf16(af0, bfr, acc1[0][nt], 0, 0, 0);
            acc1[1][nt] = __builtin_amdgcn_mfma_f32_16x16x32_bf16(af1, bfr, acc1[1][nt], 0, 0, 0);
        }
    }
    #pragma unroll
    for (int nt = 0; nt < 8; nt++) {
        int n = (wv * 8 + nt) * 16 + m16;
        float b1f = ld(b1v, n, bf);
        #pragma unroll
        for (int mt = 0; mt < 2; mt++)
            #pragma unroll
            for (int r = 0; r < 4; r++)
                h1[mt * 16 + quad * 4 + r][n] = f2bu(geluf(acc1[mt][nt][r] + b1f));
    }
    __syncthreads();
    const unsigned short* w2p = (const unsigned short*)(ws + W2P);
    floatx4 acc2[2][2];
    #pragma unroll
    for (int mt = 0; mt < 2; mt++)
        #pragma unroll
        for (int nt = 0; nt < 2; nt++)
            acc2[mt][nt] = (floatx4){0.f, 0.f, 0.f, 0.f};
    for (int kc = 0; kc < 16; kc++) {
        bhalf8 af0 = *(const bhalf8*)&h1[m16][kc * 32 + quad * 8];
        bhalf8 af1 = *(const bhalf8*)&h1[16 + m16][kc * 32 + quad * 8];
        #pragma unroll
        for (int nt = 0; nt < 2; nt++) {
            bhalf8 bfr = *(const bhalf8*)&w2p[(((kc * 8) + wv * 2 + nt) * 64 + lane) * 8];
            acc2[0][nt] = __builtin_amdgcn_mfma_f32_16x16x32_bf16(af0, bfr, acc2[0][nt], 0, 0, 0);
            acc2[1][nt] = __builtin_amdgcn_mfma_f32_16x16x32_bf16(af1, bfr, acc2[1][nt], 0, 0, 0);
        }
    }
    // round-trip C through LDS (reuse A1) for pixel-major vector epilogue
    __syncthreads();
    #pragma unroll
    for (int nt = 0; nt < 2; nt++) {
        int n = wv * 32 + nt * 16 + m16;
        #pragma unroll
        for (int mt = 0; mt < 2; mt++)
            #pragma unroll
            for (int r = 0; r < 4; r++)
                A1[mt * 16 + quad * 4 + r][n] = f2bu(acc2[mt][nt][r]);
    }
    __syncthreads();
    {
        const unsigned short* decb = (const unsigned short*)(ws + DECBF);
        const unsigned short* xub  = (const unsigned short*)(ws + XUBF);
        int pxl = tid >> 3, dc = (tid & 7) * 8;
        long long p = px0 + pxl;
        bhalf8 cre = *(const bhalf8*)&A1[pxl][dc];
        bhalf8 cim = *(const bhalf8*)&A1[pxl][64 + dc];
        bhalf8 xr8 = *(const bhalf8*)&xub[p * 128 + dc];
        bhalf8 xi8 = *(const bhalf8*)&xub[p * 128 + 64 + dc];
        bhalf8 dr8 = *(const bhalf8*)&decb[p * 128 + dc];
        bhalf8 di8 = *(const bhalf8*)&decb[p * 128 + 64 + dc];
        float zr[8], zi[8];
        #pragma unroll
        for (int k = 0; k < 8; k++) {
            zr[k] = bu2f((unsigned short)cre[k]) + gb2[dc + k]
                  + bu2f((unsigned short)xr8[k]) + bu2f((unsigned short)dr8[k]);
            zi[k] = bu2f((unsigned short)cim[k]) + gb2[64 + dc + k]
                  + bu2f((unsigned short)xi8[k]) + bu2f((unsigned short)di8[k]);
        }
        if (bf) {
            unsigned short o[16];
            #pragma unroll
            for (int k = 0; k < 8; k++) { o[2 * k] = f2bu(zr[k]); o[2 * k + 1] = f2bu(zi[k]); }
            unsigned short* ob = (unsigned short*)outv;
            *(bhalf8*)&ob[ZOUT + p * 128 + 2 * dc]     = *(bhalf8*)&o[0];
            *(bhalf8*)&ob[ZOUT + p * 128 + 2 * dc + 8] = *(bhalf8*)&o[8];
        } else {
            float* of = (float*)outv + ZOUT + p * 128 + 2 * dc;
            #pragma unroll
            for (int k = 0; k < 8; k++) { of[2 * k] = zr[k]; of[2 * k + 1] = zi[k]; }
        }
    }
}

extern "C" void kernel_launch(void* const* d_in, const int* in_sizes, int n_in,
                              void* d_out, int out_size, void* d_ws, size_t ws_size,
                              hipStream_t stream) {
    const void* x_re  = d_in[0];
    const void* x_im  = d_in[1];
    const void* h_re  = d_in[2];
    const void* h_im  = d_in[3];
    const void* fl_re = d_in[4];
    const void* fl_im = d_in[5];
    const void* dtseq = d_in[6];
    const void* g_s   = d_in[7];
    const void* b_s   = d_in[8];
    const void* Wc    = d_in[9];
    const void* bc    = d_in[10];
    const void* g_t   = d_in[11];
    const void* b_t   = d_in[12];
    const void* E_re  = d_in[13];
    const void* E_im  = d_in[14];
    const void* De_re = d_in[15];
    const void* De_im = d_in[16];
    const void* lamfl = d_in[17];
    const void* Ws_re = d_in[18];
    const void* Ws_im = d_in[19];
    const void* wgate = d_in[20];
    const void* bgate = d_in[21];
    const void* lamrr = d_in[22];
    const void* lamim = d_in[23];
    const void* W1    = d_in[24];
    const void* b1    = d_in[25];
    const void* W2    = d_in[26];
    const void* b2    = d_in[27];
    float* ws = (float*)d_ws;

    hipMemsetAsync((char*)d_ws + XMEAN * sizeof(float), 0, 4096 * sizeof(float), stream);
    k_detect<<<1, 64, 0, stream>>>((const unsigned short*)x_re, ws);
    k_convert<<<1216, 256, 0, stream>>>(Wc, W1, W2, E_re, E_im, De_re, De_im, ws);
    kA_ln<<<2048, 256, 0, stream>>>(x_re, x_im, g_s, b_s, ws);
    kB_conv<<<2048, 256, 0, stream>>>(bc, ws);
    kC_eig<<<2048, 256, 0, stream>>>(ws);
    kD_flux<<<2, 256, 0, stream>>>(fl_re, fl_im, dtseq, lamfl, Ws_re, Ws_im,
                                   wgate, bgate, lamrr, lamim, ws, d_out);
    kE_scan<<<2048, 256, 0, stream>>>(h_re, h_im, ws, d_out);
    kF1_dec<<<2048, 256, 0, stream>>>(g_t, b_t, ws);
    kMLP<<<4096, 256, 0, stream>>>(b1, b2, ws, d_out);
}